// Round 5
// baseline (77.317 us; speedup 1.0000x reference)
//
#include <hip/hip_runtime.h>
#include <hip/hip_bf16.h>
#include <math.h>

#define DD 256
#define BB 8
#define TT 1024
#define MM (BB*TT)
#define NH 4
#define DKH 64
#define NQ 3

typedef __attribute__((ext_vector_type(8))) short bf16x8;
typedef __attribute__((ext_vector_type(4))) float f32x4;
typedef unsigned short u16;
typedef unsigned int u32;

__device__ __forceinline__ float bf2f(u16 u) {
  return __uint_as_float(((u32)u) << 16);
}
__device__ __forceinline__ u16 f2bf(float x) {
  __hip_bfloat16 h = __float2bfloat16(x);
  return *reinterpret_cast<u16*>(&h);
}
__device__ __forceinline__ uint2 pack4(float a, float b, float c, float d) {
  uint2 r;
  r.x = (u32)f2bf(a) | ((u32)f2bf(b) << 16);
  r.y = (u32)f2bf(c) | ((u32)f2bf(d) << 16);
  return r;
}
__device__ __forceinline__ float wred(float v) {
#pragma unroll
  for (int off = 32; off; off >>= 1) v += __shfl_xor(v, off);
  return v;
}

// ---------------------------------------------------------------------------
// Precast: x (8192x256 fp32) and 9 weight matrices (256x256 fp32) -> bf16.
// Each thread converts 8 consecutive elements. One-shot, memory-bound.
// ---------------------------------------------------------------------------
#define NX8 (MM * DD / 8)      // 262144 chunks for x
#define NW8 (65536 / 8)        // 8192 chunks per matrix
#define NCHUNK (NX8 + 9 * NW8) // 335872

__global__ __launch_bounds__(256) void precast(
    const float* __restrict__ x,
    const float* __restrict__ w0, const float* __restrict__ w1,
    const float* __restrict__ w2, const float* __restrict__ w3,
    const float* __restrict__ w4, const float* __restrict__ w5,
    const float* __restrict__ w6, const float* __restrict__ w7,
    const float* __restrict__ w8_, u16* __restrict__ wb,
    u16* __restrict__ xb)
{
  const int c = blockIdx.x * 256 + threadIdx.x;
  if (c >= NCHUNK) return;
  const float* src;
  u16* dst;
  int off;
  if (c < NX8) {
    src = x; dst = xb; off = c * 8;
  } else {
    const int r = c - NX8;
    const int mi = r / NW8;
    off = (r - mi * NW8) * 8;
    switch (mi) {
      case 0: src = w0; break; case 1: src = w1; break;
      case 2: src = w2; break; case 3: src = w3; break;
      case 4: src = w4; break; case 5: src = w5; break;
      case 6: src = w6; break; case 7: src = w7; break;
      default: src = w8_; break;
    }
    dst = wb + mi * 65536;
  }
  const float4 v0 = *(const float4*)(src + off);
  const float4 v1 = *(const float4*)(src + off + 4);
  *(uint2*)(dst + off)     = pack4(v0.x, v0.y, v0.z, v0.w);
  *(uint2*)(dst + off + 4) = pack4(v1.x, v1.y, v1.z, v1.w);
}

// ---------------------------------------------------------------------------
// Single-stage GEMM: out[M,256] = act(A[M,256] @ W[256,256]^T + bias).
// A and W both bf16 -> staging is pure uint4 copy.
// ---------------------------------------------------------------------------
template<int ACT>   // 0 = none, 1 = ELU
__global__ __launch_bounds__(256) void gemm64(const u16* __restrict__ A_,
                                              const u16* __restrict__ W,
                                              const float* __restrict__ bias,
                                              u16* __restrict__ out)
{
  __shared__ u16 As[64][264];
  __shared__ u16 Bs[64][264];
  const int tid  = threadIdx.x;
  const int lane = tid & 63, wave = tid >> 6;
  const int wr = wave >> 1, wc = wave & 1;
  const int q  = lane >> 4, lr = lane & 15;
  const int m0 = blockIdx.x * 64, n0 = blockIdx.y * 64;

#pragma unroll
  for (int p = 0; p < 8; ++p) {
    const int c = tid + p * 256;
    const int row = c >> 5, col = (c & 31) * 8;
    *(uint4*)&As[row][col] = *(const uint4*)(A_ + (size_t)(m0 + row) * DD + col);
    *(uint4*)&Bs[row][col] = *(const uint4*)(W  + (size_t)(n0 + row) * DD + col);
  }
  __syncthreads();

  f32x4 acc[2][2] = {};
#pragma unroll
  for (int kk = 0; kk < 8; ++kk) {
    const int koff = kk * 32 + q * 8;
    bf16x8 av[2], bv[2];
    av[0] = *(const bf16x8*)&As[wr * 32 + lr][koff];
    av[1] = *(const bf16x8*)&As[wr * 32 + 16 + lr][koff];
    bv[0] = *(const bf16x8*)&Bs[wc * 32 + lr][koff];
    bv[1] = *(const bf16x8*)&Bs[wc * 32 + 16 + lr][koff];
#pragma unroll
    for (int i = 0; i < 2; ++i)
#pragma unroll
      for (int j = 0; j < 2; ++j)
        acc[i][j] = __builtin_amdgcn_mfma_f32_16x16x32_bf16(av[i], bv[j], acc[i][j], 0, 0, 0);
  }

#pragma unroll
  for (int i = 0; i < 2; ++i) {
#pragma unroll
    for (int j = 0; j < 2; ++j) {
      const int col = n0 + wc * 32 + j * 16 + lr;
      const float bvv = bias ? bias[col] : 0.f;
#pragma unroll
      for (int t = 0; t < 4; ++t) {
        const int row = m0 + wr * 32 + i * 16 + q * 4 + t;
        float v = acc[i][j][t] + bvv;
        if (ACT == 1) v = v > 0.f ? v : expm1f(v);
        out[(size_t)row * DD + col] = f2bf(v);
      }
    }
  }
}

// ---------------------------------------------------------------------------
// Fused K/V projection, single-stage, all-bf16. blockIdx.y: 0-3 K, 4-7 V.
// ---------------------------------------------------------------------------
__global__ __launch_bounds__(256) void gemm_kv(const u16* __restrict__ A_,
                                               const u16* __restrict__ Wk,
                                               const u16* __restrict__ Wv,
                                               u16* __restrict__ kout,
                                               u16* __restrict__ vout)
{
  __shared__ u16 As[64][264];
  __shared__ u16 Bs[64][264];
  const int tid  = threadIdx.x;
  const int lane = tid & 63, wave = tid >> 6;
  const int wr = wave >> 1, wc = wave & 1;
  const int q  = lane >> 4, lr = lane & 15;
  const int ny = blockIdx.y;
  const u16* W = (ny < 4) ? Wk : Wv;
  u16* out = (ny < 4) ? kout : vout;
  const int m0 = blockIdx.x * 64, n0 = (ny & 3) * 64;

#pragma unroll
  for (int p = 0; p < 8; ++p) {
    const int c = tid + p * 256;
    const int row = c >> 5, col = (c & 31) * 8;
    *(uint4*)&As[row][col] = *(const uint4*)(A_ + (size_t)(m0 + row) * DD + col);
    *(uint4*)&Bs[row][col] = *(const uint4*)(W  + (size_t)(n0 + row) * DD + col);
  }
  __syncthreads();

  f32x4 acc[2][2] = {};
#pragma unroll
  for (int kk = 0; kk < 8; ++kk) {
    const int koff = kk * 32 + q * 8;
    bf16x8 av[2], bv[2];
    av[0] = *(const bf16x8*)&As[wr * 32 + lr][koff];
    av[1] = *(const bf16x8*)&As[wr * 32 + 16 + lr][koff];
    bv[0] = *(const bf16x8*)&Bs[wc * 32 + lr][koff];
    bv[1] = *(const bf16x8*)&Bs[wc * 32 + 16 + lr][koff];
#pragma unroll
    for (int i = 0; i < 2; ++i)
#pragma unroll
      for (int j = 0; j < 2; ++j)
        acc[i][j] = __builtin_amdgcn_mfma_f32_16x16x32_bf16(av[i], bv[j], acc[i][j], 0, 0, 0);
  }

#pragma unroll
  for (int i = 0; i < 2; ++i) {
#pragma unroll
    for (int j = 0; j < 2; ++j) {
      const int col = n0 + wc * 32 + j * 16 + lr;
#pragma unroll
      for (int t = 0; t < 4; ++t) {
        const int row = m0 + wr * 32 + i * 16 + q * 4 + t;
        out[(size_t)row * DD + col] = f2bf(acc[i][j][t]);
      }
    }
  }
}

// ---------------------------------------------------------------------------
// K3: gate = eta2 @ gw^T + gb; h = LN(x + sigmoid(gate)*eta2) fused.
// W is bf16 now.
// ---------------------------------------------------------------------------
__global__ __launch_bounds__(256) void grn_gate_ln(
    const u16* __restrict__ eta2, const u16* __restrict__ W,
    const float* __restrict__ gb, const float* __restrict__ x,
    const float* __restrict__ lng, const float* __restrict__ lnb,
    u16* __restrict__ hout, float* __restrict__ hlast)
{
  __shared__ u16 As[32][136];
  __shared__ u16 Bs[256][136];
  __shared__ float red_s[32][5];
  __shared__ float red_q[32][5];
  __shared__ float smean[32], srstd[32];

  const int tid  = threadIdx.x;
  const int lane = tid & 63, wave = tid >> 6;
  const int q  = lane >> 4, lr = lane & 15;
  const int m0 = blockIdx.x * 32;

  f32x4 acc[2][4] = {};

  for (int k0 = 0; k0 < DD; k0 += 128) {
#pragma unroll
    for (int p = 0; p < 2; ++p) {
      const int c = tid + p * 256;
      const int row = c >> 4, col = (c & 15) * 8;
      *(uint4*)&As[row][col] = *(const uint4*)(eta2 + (size_t)(m0 + row) * DD + k0 + col);
    }
#pragma unroll
    for (int p = 0; p < 16; ++p) {
      const int c = tid + p * 256;
      const int row = c >> 4, col = (c & 15) * 8;
      *(uint4*)&Bs[row][col] = *(const uint4*)(W + (size_t)row * DD + k0 + col);
    }
    __syncthreads();
#pragma unroll
    for (int kk = 0; kk < 4; ++kk) {
      const int koff = kk * 32 + q * 8;
      bf16x8 av[2], bv[4];
#pragma unroll
      for (int i = 0; i < 2; ++i) av[i] = *(const bf16x8*)&As[i * 16 + lr][koff];
#pragma unroll
      for (int j = 0; j < 4; ++j) bv[j] = *(const bf16x8*)&Bs[wave * 64 + j * 16 + lr][koff];
#pragma unroll
      for (int i = 0; i < 2; ++i)
#pragma unroll
        for (int j = 0; j < 4; ++j)
          acc[i][j] = __builtin_amdgcn_mfma_f32_16x16x32_bf16(av[i], bv[j], acc[i][j], 0, 0, 0);
    }
    __syncthreads();
  }

  float pre[2][4][4];
#pragma unroll
  for (int i = 0; i < 2; ++i) {
#pragma unroll
    for (int j = 0; j < 4; ++j) {
      const int n = wave * 64 + j * 16 + lr;
      const float gbn = gb[n];
#pragma unroll
      for (int t = 0; t < 4; ++t) {
        const int grow = m0 + i * 16 + q * 4 + t;
        const float gate = acc[i][j][t] + gbn;
        const float sig = 1.f / (1.f + expf(-gate));
        const float e2 = bf2f(eta2[(size_t)grow * DD + n]);
        pre[i][j][t] = x[(size_t)grow * DD + n] + sig * e2;
      }
    }
  }
#pragma unroll
  for (int i = 0; i < 2; ++i) {
#pragma unroll
    for (int t = 0; t < 4; ++t) {
      float s = 0.f, sq = 0.f;
#pragma unroll
      for (int j = 0; j < 4; ++j) { const float v = pre[i][j][t]; s += v; sq += v * v; }
#pragma unroll
      for (int m = 1; m <= 8; m <<= 1) { s += __shfl_xor(s, m); sq += __shfl_xor(sq, m); }
      if (lr == 0) {
        const int ml = i * 16 + q * 4 + t;
        red_s[ml][wave] = s;
        red_q[ml][wave] = sq;
      }
    }
  }
  __syncthreads();
  if (tid < 32) {
    const float s  = red_s[tid][0] + red_s[tid][1] + red_s[tid][2] + red_s[tid][3];
    const float sq = red_q[tid][0] + red_q[tid][1] + red_q[tid][2] + red_q[tid][3];
    const float mean = s * (1.f / DD);
    const float var = sq * (1.f / DD) - mean * mean;
    smean[tid] = mean;
    srstd[tid] = rsqrtf(var + 1e-5f);
  }
  __syncthreads();
#pragma unroll
  for (int i = 0; i < 2; ++i) {
#pragma unroll
    for (int j = 0; j < 4; ++j) {
      const int n = wave * 64 + j * 16 + lr;
      const float gn = lng[n], bn = lnb[n];
#pragma unroll
      for (int t = 0; t < 4; ++t) {
        const int ml = i * 16 + q * 4 + t;
        const int grow = m0 + ml;
        const float hn = (pre[i][j][t] - smean[ml]) * srstd[ml] * gn + bn;
        hout[(size_t)grow * DD + n] = f2bf(hn);
        if ((grow & (TT - 1)) == (TT - 1))
          hlast[(size_t)(grow >> 10) * DD + n] = hn;
      }
    }
  }
}

// ---------------------------------------------------------------------------
// Attention: q, scores, softmax, per-head ctx. grid (NH, BB).
// ---------------------------------------------------------------------------
__global__ __launch_bounds__(256) void qk_softmax_ctx(
    const float* __restrict__ hlast, const u16* __restrict__ kbuf,
    const u16* __restrict__ vbuf, const float* __restrict__ wq,
    float* __restrict__ ctxbuf)
{
  __shared__ float hl[DD], qh[DKH];
  __shared__ float red[8];
  __shared__ float pr[TT];
  __shared__ float part[8][DKH];
  const int h = blockIdx.x, b = blockIdx.y;
  const int tid = threadIdx.x, lane = tid & 63, w = tid >> 6;

  hl[tid] = hlast[(size_t)b * DD + tid];
  __syncthreads();
  {
    const int j = tid >> 2, seg = tid & 3;
    const float* wr = wq + (size_t)(h * DKH + j) * DD + seg * 64;
    const float* sp = hl + seg * 64;
    float acc = 0.f;
#pragma unroll
    for (int k = 0; k < 64; k += 4) {
      const float4 w4 = *(const float4*)(wr + k);
      acc += w4.x * sp[k] + w4.y * sp[k + 1] + w4.z * sp[k + 2] + w4.w * sp[k + 3];
    }
    acc += __shfl_xor(acc, 1);
    acc += __shfl_xor(acc, 2);
    if (seg == 0) qh[j] = acc;
  }
  __syncthreads();

  float sv[4], mx = -3.0e38f;
#pragma unroll
  for (int i = 0; i < 4; ++i) {
    const int s = tid + 256 * i;
    const u16* kr = kbuf + ((size_t)(b * TT + s)) * DD + h * DKH;
    float acc = 0.f;
#pragma unroll
    for (int d = 0; d < DKH; d += 8) {
      const bf16x8 kv = *(const bf16x8*)(kr + d);
#pragma unroll
      for (int e = 0; e < 8; ++e) acc += bf2f((u16)kv[e]) * qh[d + e];
    }
    sv[i] = acc * 0.125f;
    mx = fmaxf(mx, sv[i]);
  }
#pragma unroll
  for (int off = 32; off; off >>= 1) mx = fmaxf(mx, __shfl_xor(mx, off));
  if (lane == 0) red[w] = mx;
  __syncthreads();
  mx = fmaxf(fmaxf(red[0], red[1]), fmaxf(red[2], red[3]));
  float sum = 0.f;
#pragma unroll
  for (int i = 0; i < 4; ++i) { sv[i] = expf(sv[i] - mx); sum += sv[i]; }
  sum = wred(sum);
  if (lane == 0) red[4 + w] = sum;
  __syncthreads();
  const float inv = 1.f / (red[4] + red[5] + red[6] + red[7]);
#pragma unroll
  for (int i = 0; i < 4; ++i) pr[tid + 256 * i] = sv[i] * inv;
  __syncthreads();

  {
    const int np = (tid & 31) * 2, sg = tid >> 5;
    const u16* vp = vbuf + ((size_t)(b * TT + sg * 128)) * DD + h * DKH + np;
    const float* pp = pr + sg * 128;
    float a0 = 0.f, a1 = 0.f;
    for (int s = 0; s < 128; ++s) {
      const u32 vv = *(const u32*)(vp + (size_t)s * DD);
      const float p = pp[s];
      a0 += p * bf2f((u16)(vv & 0xffffu));
      a1 += p * bf2f((u16)(vv >> 16));
    }
    part[sg][np] = a0; part[sg][np + 1] = a1;
  }
  __syncthreads();
  if (tid < DKH) {
    float s = 0.f;
#pragma unroll
    for (int g = 0; g < 8; ++g) s += part[g][tid];
    ctxbuf[(size_t)b * DD + h * DKH + tid] = s;
  }
}

// ---------------------------------------------------------------------------
// Coalesced matvec: 16 waves x 16 rows; 32-lane halves own a row each iter.
// ---------------------------------------------------------------------------
__device__ __forceinline__ void mv256b(const u16* __restrict__ W16,
                                       const float* __restrict__ srcbuf,
                                       float* __restrict__ dst,
                                       int wave, int lane)
{
  const int half = lane >> 5, l32 = lane & 31;
  float s[8];
  {
    const float4 s0 = *(const float4*)(srcbuf + l32 * 8);
    const float4 s1 = *(const float4*)(srcbuf + l32 * 8 + 4);
    s[0] = s0.x; s[1] = s0.y; s[2] = s0.z; s[3] = s0.w;
    s[4] = s1.x; s[5] = s1.y; s[6] = s1.z; s[7] = s1.w;
  }
#pragma unroll
  for (int i = 0; i < 8; ++i) {
    const int r = wave * 16 + i * 2 + half;
    const bf16x8 wv = *(const bf16x8*)(W16 + (size_t)r * DD + l32 * 8);
    float acc = 0.f;
#pragma unroll
    for (int e = 0; e < 8; ++e) acc += bf2f((u16)wv[e]) * s[e];
#pragma unroll
    for (int off = 16; off; off >>= 1) acc += __shfl_xor(acc, off);
    if (l32 == 0) dst[r] = acc;
  }
}

#define LN_STEP(val, gam, bet, dst) \
  __syncthreads(); \
  if (tid < DD) { lnS[tid] = (val); lnQ[tid] = (val) * (val); } \
  __syncthreads(); \
  if (tid < 64) { \
    float s_ = 0.f, q_ = 0.f; \
    _Pragma("unroll") \
    for (int i_ = 0; i_ < 4; ++i_) { s_ += lnS[tid + 64 * i_]; q_ += lnQ[tid + 64 * i_]; } \
    s_ = wred(s_); q_ = wred(q_); \
    if (tid == 0) { const float m_ = s_ * (1.f / DD); red2[0] = m_; red2[1] = rsqrtf(q_ * (1.f / DD) - m_ * m_ + 1e-5f); } \
  } \
  __syncthreads(); \
  if (tid < DD) dst[tid] = ((val) - red2[0]) * red2[1] * gam[tid] + bet[tid]; \
  __syncthreads();

// ---------------------------------------------------------------------------
// Tail: out-proj + LN + GRN2 + quantile head. grid(BB), 1024 threads.
// ---------------------------------------------------------------------------
__global__ __launch_bounds__(1024) void tail2(
    const float* __restrict__ hlast, const float* __restrict__ ctxbuf,
    const u16* __restrict__ wbf,
    const float* __restrict__ wob, const float* __restrict__ alng, const float* __restrict__ alnb,
    const float* __restrict__ f1b, const float* __restrict__ f2b,
    const float* __restrict__ gbv, const float* __restrict__ lng, const float* __restrict__ lnb,
    const float* __restrict__ qhw, const float* __restrict__ qhb,
    float* __restrict__ out)
{
  __shared__ float hl[DD], bufA[DD], bufB[DD], bufC[DD], part0[DD];
  __shared__ float lnS[DD], lnQ[DD];
  __shared__ float red2[2];
  const int b = blockIdx.x, tid = threadIdx.x;
  const int wave = tid >> 6, lane = tid & 63;

  if (tid < DD) {
    hl[tid]   = hlast[(size_t)b * DD + tid];
    bufB[tid] = ctxbuf[(size_t)b * DD + tid];
  }
  __syncthreads();

  mv256b(wbf + 0 * 65536, bufB, part0, wave, lane);
  __syncthreads();
  float v = 0.f;
  if (tid < DD) v = hl[tid] + part0[tid] + wob[tid];
  LN_STEP(v, alng, alnb, bufA)

  mv256b(wbf + 1 * 65536, bufA, part0, wave, lane);
  __syncthreads();
  if (tid < DD) {
    const float e1 = part0[tid] + f1b[tid];
    bufB[tid] = e1 > 0.f ? e1 : expm1f(e1);
  }
  __syncthreads();

  mv256b(wbf + 2 * 65536, bufB, part0, wave, lane);
  __syncthreads();
  if (tid < DD) bufC[tid] = part0[tid] + f2b[tid];
  __syncthreads();

  mv256b(wbf + 3 * 65536, bufC, part0, wave, lane);
  __syncthreads();
  v = 0.f;
  if (tid < DD) {
    const float g = part0[tid] + gbv[tid];
    v = bufA[tid] + (1.f / (1.f + expf(-g))) * bufC[tid];
  }
  LN_STEP(v, lng, lnb, bufA)

  if (tid < 64 * NQ) {
    const int qi = tid >> 6, l = tid & 63;
    float acc = 0.f;
#pragma unroll
    for (int i = 0; i < 4; ++i) acc += qhw[(size_t)qi * DD + l + 64 * i] * bufA[l + 64 * i];
    acc = wred(acc);
    if (l == 0) out[b * NQ + qi] = acc + qhb[qi];
  }
}

// ---------------------------------------------------------------------------
extern "C" void kernel_launch(void* const* d_in, const int* in_sizes, int n_in,
                              void* d_out, int out_size, void* d_ws, size_t ws_size,
                              hipStream_t stream)
{
  const float* x       = (const float*)d_in[0];
  const float* g1_f1w  = (const float*)d_in[1];
  const float* g1_f1b  = (const float*)d_in[2];
  const float* g1_f2w  = (const float*)d_in[3];
  const float* g1_f2b  = (const float*)d_in[4];
  const float* g1_gw   = (const float*)d_in[5];
  const float* g1_gb   = (const float*)d_in[6];
  const float* g1_lng  = (const float*)d_in[7];
  const float* g1_lnb  = (const float*)d_in[8];
  const float* wq      = (const float*)d_in[9];
  const float* wk      = (const float*)d_in[10];
  const float* wv      = (const float*)d_in[11];
  const float* wo_w    = (const float*)d_in[12];
  const float* wo_b    = (const float*)d_in[13];
  const float* attn_lng= (const float*)d_in[14];
  const float* attn_lnb= (const float*)d_in[15];
  const float* g2_f1w  = (const float*)d_in[16];
  const float* g2_f1b  = (const float*)d_in[17];
  const float* g2_f2w  = (const float*)d_in[18];
  const float* g2_f2b  = (const float*)d_in[19];
  const float* g2_gw   = (const float*)d_in[20];
  const float* g2_gb   = (const float*)d_in[21];
  const float* g2_lng  = (const float*)d_in[22];
  const float* g2_lnb  = (const float*)d_in[23];
  const float* qh_w    = (const float*)d_in[24];
  const float* qh_b    = (const float*)d_in[25];
  float* out = (float*)d_out;

  char* w8 = (char*)d_ws;
  // bf16 weights: [0]=g1_f1w [1]=g1_f2w [2]=g1_gw [3]=wk [4]=wv
  //               [5]=wo_w [6]=g2_f1w [7]=g2_f2w [8]=g2_gw
  u16*  wb    = (u16*)(w8);                          // 9 * 128 KB = 1.125 MB
  u16*  xb    = (u16*)(w8 + ((size_t)2  << 20));     // 4 MB
  u16*  eta1  = (u16*)(w8 + ((size_t)6  << 20));
  u16*  eta2  = (u16*)(w8 + ((size_t)10 << 20));
  u16*  hbuf  = (u16*)(w8 + ((size_t)14 << 20));
  u16*  kbuf  = (u16*)(w8 + ((size_t)18 << 20));
  u16*  vbuf  = (u16*)(w8 + ((size_t)22 << 20));
  float* hlast = (float*)(w8 + ((size_t)26 << 20));
  float* ctxbuf = (float*)(w8 + ((size_t)26 << 20) + (64 << 10));

  const dim3 blk(256);
  const dim3 g1(MM / 64, DD / 64);

  precast<<<dim3((NCHUNK + 255) / 256), blk, 0, stream>>>(
      x, g1_f1w, g1_f2w, g1_gw, wk, wv, wo_w, g2_f1w, g2_f2w, g2_gw, wb, xb);
  gemm64<1><<<g1, blk, 0, stream>>>(xb,   wb + 0 * 65536, g1_f1b, eta1);
  gemm64<0><<<g1, blk, 0, stream>>>(eta1, wb + 1 * 65536, g1_f2b, eta2);
  grn_gate_ln<<<dim3(MM / 32), blk, 0, stream>>>(eta2, wb + 2 * 65536, g1_gb, x,
                                                 g1_lng, g1_lnb, hbuf, hlast);
  gemm_kv<<<dim3(MM / 64, 8), blk, 0, stream>>>(hbuf, wb + 3 * 65536, wb + 4 * 65536,
                                                kbuf, vbuf);
  qk_softmax_ctx<<<dim3(NH, BB), blk, 0, stream>>>(hlast, kbuf, vbuf, wq, ctxbuf);
  tail2<<<dim3(BB), dim3(1024), 0, stream>>>(hlast, ctxbuf, wb + 5 * 65536,
                                             wo_b, attn_lng, attn_lnb,
                                             g2_f1b, g2_f2b, g2_gb, g2_lng, g2_lnb,
                                             qh_w, qh_b, out);
}